// Round 1
// baseline (161.555 us; speedup 1.0000x reference)
//
#include <hip/hip_runtime.h>
#include <cstddef>
#include <cstdint>

#define B_ 32
#define C_ 64
#define HW_ 16384
#define K_ 64
#define PC_ 3
#define NCH_ 16
#define PXCH_ 1024
#define TILE_ 64
#define NTILE_ (PXCH_/TILE_)
#define LDF_ 68
#define INV_N_ (1.0f/49152.0f)

// ---- workspace layout (float indices) ----
#define Q_OFF_    ((size_t)0)
#define Q_SZ_     ((size_t)4096*64)
#define IDX_OFF_  (Q_OFF_ + Q_SZ_)          // 32 ints live here
#define DATA_OFF_ (IDX_OFF_ + 64)
// partial (deterministic) mode
#define MPART_OFF_ DATA_OFF_
#define MPART_SZ_  ((size_t)B_*NCH_*4096)
#define VPART_OFF_ (MPART_OFF_ + MPART_SZ_)
#define VPART_SZ_  ((size_t)B_*NCH_*192)
#define RPART_OFF_ (VPART_OFF_ + VPART_SZ_)
#define PARTIAL_END_ (RPART_OFF_ + (size_t)B_*NCH_)
// atomic (small-ws fallback) mode
#define MFULL_OFF_ DATA_OFF_
#define VFULL_OFF_ (MFULL_OFF_ + (size_t)B_*4096)
#define RFULL_OFF_ (VFULL_OFF_ + (size_t)B_*192)
#define ATOMIC_END_ (RFULL_OFF_ + B_)

// ---- output layout (float indices) ----
#define OUT_DM_   ((size_t)B_*PC_*HW_)      // 1572864
#define OUT_IDX_  (OUT_DM_ + (size_t)B_*K_)
#define OUT_LOSS_ (OUT_IDX_ + B_)
#define OUT_DIST_ (OUT_LOSS_ + B_)

// Q[ij][k] = sum_pc w[3k+pc][i] * w[3k+pc][j],  ij = i*64+j, flat = ij*64+k
__global__ __launch_bounds__(256)
void kpre_q(const float* __restrict__ weight, float* __restrict__ ws) {
    int e  = blockIdx.x * 256 + threadIdx.x;   // 262144 total
    int k  = e & 63;
    int ij = e >> 6;
    int i  = ij >> 6, j = ij & 63;
    float s = 0.f;
#pragma unroll
    for (int pc = 0; pc < PC_; ++pc) {
        const float* row = weight + (size_t)(3*k + pc) * 64;
        s += row[i] * row[j];
    }
    ws[Q_OFF_ + e] = s;
}

// K1: per (b, chunk) accumulate M = sum f f^T, v = sum f*r, rsum = sum r^2
template<bool PARTIAL>
__global__ __launch_bounds__(256)
void k1_stats(const float* __restrict__ feat, const float* __restrict__ target,
              const float* __restrict__ pred, float* __restrict__ ws) {
    const int b     = blockIdx.x >> 4;
    const int chunk = blockIdx.x & 15;
    const int t  = threadIdx.x;
    const int px = t & 63;
    const int wv = t >> 6;        // wave id 0..3
    const int ti = t >> 4;        // row-chunk 0..15
    const int tj = t & 15;        // col-chunk 0..15
    const int vc = t & 63, vpc = t >> 6;   // v-loop roles (t<192)

    __shared__ float fT[TILE_][LDF_];
    __shared__ float rT[TILE_][4];
    __shared__ float rred[4];

    float acc[4][4];
#pragma unroll
    for (int q = 0; q < 4; ++q)
#pragma unroll
        for (int r = 0; r < 4; ++r) acc[q][r] = 0.f;
    float vacc = 0.f;
    float rsq  = 0.f;

    const size_t fbase = (size_t)b * C_ * HW_ + (size_t)chunk * PXCH_;
    const size_t tbase = (size_t)b * PC_ * HW_ + (size_t)chunk * PXCH_;

    for (int tile = 0; tile < NTILE_; ++tile) {
        const int hw0 = tile * TILE_;
        __syncthreads();
        // stage feat: thread covers px, ch = wv*16 + i (coalesced 256B per instr)
        float vals[16];
#pragma unroll
        for (int i = 0; i < 16; ++i) {
            int ch = wv * 16 + i;
            vals[i] = feat[fbase + (size_t)ch * HW_ + hw0 + px];
        }
        if (t < 192) {
            float pv = pred  [tbase + (size_t)vpc * HW_ + hw0 + vc];
            float tv = target[tbase + (size_t)vpc * HW_ + hw0 + vc];
            float r = pv - tv;
            rT[vc][vpc] = r;
            rsq += r * r;
        }
#pragma unroll
        for (int g = 0; g < 4; ++g) {
            float4 v = make_float4(vals[4*g], vals[4*g+1], vals[4*g+2], vals[4*g+3]);
            *(float4*)&fT[px][wv * 16 + 4*g] = v;
        }
        __syncthreads();
        // rank-1 updates: 16 FMA per pixel per thread
#pragma unroll 2
        for (int p = 0; p < TILE_; ++p) {
            const float4 fr = *(const float4*)&fT[p][4 * ti];
            const float4 fc = *(const float4*)&fT[p][4 * tj];
            acc[0][0] += fr.x*fc.x; acc[0][1] += fr.x*fc.y; acc[0][2] += fr.x*fc.z; acc[0][3] += fr.x*fc.w;
            acc[1][0] += fr.y*fc.x; acc[1][1] += fr.y*fc.y; acc[1][2] += fr.y*fc.z; acc[1][3] += fr.y*fc.w;
            acc[2][0] += fr.z*fc.x; acc[2][1] += fr.z*fc.y; acc[2][2] += fr.z*fc.z; acc[2][3] += fr.z*fc.w;
            acc[3][0] += fr.w*fc.x; acc[3][1] += fr.w*fc.y; acc[3][2] += fr.w*fc.z; acc[3][3] += fr.w*fc.w;
        }
        // v accumulation (threads 0..191): v[pc][c] += f[p][c]*r[p][pc]
        if (t < 192) {
#pragma unroll 4
            for (int p = 0; p < TILE_; ++p)
                vacc += fT[p][vc] * rT[p][vpc];
        }
    }

    // write/accumulate partials
    if (PARTIAL) {
        float* Mp = ws + MPART_OFF_ + (size_t)(b * NCH_ + chunk) * 4096;
#pragma unroll
        for (int q = 0; q < 4; ++q) {
            int row = 4 * ti + q;
            *(float4*)&Mp[row * 64 + 4 * tj] =
                make_float4(acc[q][0], acc[q][1], acc[q][2], acc[q][3]);
        }
        if (t < 192) ws[VPART_OFF_ + (size_t)(b * NCH_ + chunk) * 192 + t] = vacc;
    } else {
        float* Mf = ws + MFULL_OFF_ + (size_t)b * 4096;
#pragma unroll
        for (int q = 0; q < 4; ++q)
#pragma unroll
            for (int r = 0; r < 4; ++r)
                atomicAdd(&Mf[(4 * ti + q) * 64 + 4 * tj + r], acc[q][r]);
        if (t < 192) atomicAdd(&ws[VFULL_OFF_ + (size_t)b * 192 + t], vacc);
    }
    // block-reduce rsq (threads >=192 hold 0)
#pragma unroll
    for (int off = 32; off >= 1; off >>= 1) rsq += __shfl_xor(rsq, off);
    if ((t & 63) == 0) rred[wv] = rsq;
    __syncthreads();
    if (t == 0) {
        float s = rred[0] + rred[1] + rred[2] + rred[3];
        if (PARTIAL) ws[RPART_OFF_ + b * NCH_ + chunk] = s;
        else         atomicAdd(&ws[RFULL_OFF_ + b], s);
    }
}

// K2: per-b reduce partials, dist[b][k] = (<M,Q_k> + 2 w_k.v + rsum)/N
template<bool PARTIAL>
__global__ __launch_bounds__(256)
void k2_dist(const float* __restrict__ weight, const float* __restrict__ ws,
             float* __restrict__ dout) {
    const int b = blockIdx.x;
    const int t = threadIdx.x;
    __shared__ float Ml[4096];
    __shared__ float vl[192];
    __shared__ float rl;
    __shared__ float red[4][64];

    if (PARTIAL) {
        const float* Mp = ws + MPART_OFF_ + (size_t)b * NCH_ * 4096;
#pragma unroll
        for (int s = 0; s < 16; ++s) {
            int idx = s * 256 + t;
            float sum = 0.f;
#pragma unroll
            for (int ch = 0; ch < NCH_; ++ch) sum += Mp[ch * 4096 + idx];
            Ml[idx] = sum;
        }
        if (t < 192) {
            const float* vp = ws + VPART_OFF_ + (size_t)b * NCH_ * 192;
            float s = 0.f;
#pragma unroll
            for (int ch = 0; ch < NCH_; ++ch) s += vp[ch * 192 + t];
            vl[t] = s;
        }
        if (t == 255) {
            const float* rp = ws + RPART_OFF_ + b * NCH_;
            float s = 0.f;
#pragma unroll
            for (int ch = 0; ch < NCH_; ++ch) s += rp[ch];
            rl = s;
        }
    } else {
#pragma unroll
        for (int s = 0; s < 16; ++s) {
            int idx = s * 256 + t;
            Ml[idx] = ws[MFULL_OFF_ + (size_t)b * 4096 + idx];
        }
        if (t < 192) vl[t] = ws[VFULL_OFF_ + (size_t)b * 192 + t];
        if (t == 255) rl = ws[RFULL_OFF_ + b];
    }
    __syncthreads();

    const int k = t & 63, qd = t >> 6;
    const float* Q = ws + Q_OFF_;
    float acc = 0.f;
#pragma unroll 4
    for (int s = 0; s < 256; ++s) {
        int ij = qd * 1024 + s * 4;
        const float4 m = *(const float4*)&Ml[ij];
        acc += m.x * Q[(size_t)(ij + 0) * 64 + k]
             + m.y * Q[(size_t)(ij + 1) * 64 + k]
             + m.z * Q[(size_t)(ij + 2) * 64 + k]
             + m.w * Q[(size_t)(ij + 3) * 64 + k];
    }
    red[qd][k] = acc;
    __syncthreads();
    if (t < 64) {
        float f = red[0][t] + red[1][t] + red[2][t] + red[3][t];
        float vt = 0.f;
#pragma unroll
        for (int pc = 0; pc < PC_; ++pc) {
            const float* row = weight + (size_t)(3 * t + pc) * 64;
#pragma unroll
            for (int c = 0; c < C_; ++c) vt += row[c] * vl[pc * 64 + c];
        }
        dout[OUT_DM_ + b * 64 + t] = (f + 2.f * vt + rl) * INV_N_;
    }
}

// K3: argmin over k (first-min ties), write idx/loss/distances
__global__ __launch_bounds__(64)
void k3_argmin(float* __restrict__ dout, float* __restrict__ ws) {
    const int b = blockIdx.x, k = threadIdx.x;
    float d = dout[OUT_DM_ + b * 64 + k];
    int idx = k;
#pragma unroll
    for (int off = 32; off >= 1; off >>= 1) {
        float od = __shfl_xor(d, off);
        int   oi = __shfl_xor(idx, off);
        if (od < d || (od == d && oi < idx)) { d = od; idx = oi; }
    }
    if (k == 0) {
        ((int*)ws)[IDX_OFF_ + b] = idx;
        dout[OUT_IDX_  + b] = (float)idx;
        dout[OUT_LOSS_ + b] = d;   // loss == distances mathematically
        dout[OUT_DIST_ + b] = d;
    }
}

// K4: recompute winning candidate only; predicts = f.w_best + predict_last
__global__ __launch_bounds__(256)
void k4_pred(const float* __restrict__ feat, const float* __restrict__ predl,
             const float* __restrict__ weight, const float* __restrict__ ws,
             float* __restrict__ dout) {
    const int b   = blockIdx.x >> 4;
    const int blk = blockIdx.x & 15;
    const int t   = threadIdx.x;
    __shared__ float wl[PC_][64];
    const int kbest = ((const int*)ws)[IDX_OFF_ + b];
    if (t < 192) {
        int pc = t >> 6, c = t & 63;
        wl[pc][c] = weight[(size_t)(kbest * 3 + pc) * 64 + c];
    }
    __syncthreads();
    const int hw4 = blk * 256 + t;            // float4 index within image
    const float4* f4 = (const float4*)feat;
    const size_t base4 = (size_t)b * C_ * 4096 + hw4;
    float4 a0 = {0,0,0,0}, a1 = {0,0,0,0}, a2 = {0,0,0,0};
#pragma unroll 4
    for (int c = 0; c < C_; ++c) {
        const float4 f = f4[base4 + (size_t)c * 4096];
        const float w0 = wl[0][c], w1 = wl[1][c], w2 = wl[2][c];
        a0.x += f.x*w0; a0.y += f.y*w0; a0.z += f.z*w0; a0.w += f.w*w0;
        a1.x += f.x*w1; a1.y += f.y*w1; a1.z += f.z*w1; a1.w += f.w*w1;
        a2.x += f.x*w2; a2.y += f.y*w2; a2.z += f.z*w2; a2.w += f.w*w2;
    }
    const float4* p4 = (const float4*)predl;
    float4* o4 = (float4*)dout;
    const size_t ob = (size_t)b * PC_ * 4096 + hw4;
    float4 pl;
    pl = p4[ob];             a0.x += pl.x; a0.y += pl.y; a0.z += pl.z; a0.w += pl.w; o4[ob]          = a0;
    pl = p4[ob + 4096];      a1.x += pl.x; a1.y += pl.y; a1.z += pl.z; a1.w += pl.w; o4[ob + 4096]   = a1;
    pl = p4[ob + 8192];      a2.x += pl.x; a2.y += pl.y; a2.z += pl.z; a2.w += pl.w; o4[ob + 8192]   = a2;
}

extern "C" void kernel_launch(void* const* d_in, const int* in_sizes, int n_in,
                              void* d_out, int out_size, void* d_ws, size_t ws_size,
                              hipStream_t stream) {
    const float* feat   = (const float*)d_in[0];
    const float* target = (const float*)d_in[1];
    const float* predl  = (const float*)d_in[2];
    const float* weight = (const float*)d_in[3];
    float* out = (float*)d_out;
    float* wsf = (float*)d_ws;

    const bool partial = ws_size >= PARTIAL_END_ * sizeof(float);

    hipLaunchKernelGGL(kpre_q, dim3(1024), dim3(256), 0, stream, weight, wsf);
    if (partial) {
        hipLaunchKernelGGL((k1_stats<true>),  dim3(B_ * NCH_), dim3(256), 0, stream,
                           feat, target, predl, wsf);
        hipLaunchKernelGGL((k2_dist<true>),   dim3(B_), dim3(256), 0, stream,
                           weight, wsf, out);
    } else {
        hipMemsetAsync(wsf + DATA_OFF_, 0,
                       (ATOMIC_END_ - DATA_OFF_) * sizeof(float), stream);
        hipLaunchKernelGGL((k1_stats<false>), dim3(B_ * NCH_), dim3(256), 0, stream,
                           feat, target, predl, wsf);
        hipLaunchKernelGGL((k2_dist<false>),  dim3(B_), dim3(256), 0, stream,
                           weight, wsf, out);
    }
    hipLaunchKernelGGL(k3_argmin, dim3(B_), dim3(64), 0, stream, out, wsf);
    hipLaunchKernelGGL(k4_pred, dim3(B_ * 16), dim3(256), 0, stream,
                       feat, predl, weight, wsf, out);
}

// Round 2
// 145.172 us; speedup vs baseline: 1.1129x; 1.1129x over previous
//
#include <hip/hip_runtime.h>
#include <cstddef>
#include <cstdint>

#define B_ 32
#define C_ 64
#define HW_ 16384
#define HW4_ 4096
#define K_ 64
#define PC_ 3
#define INV_N_ (1.0f/49152.0f)

// ---- output layout (float indices) ----
#define OUT_DM_   ((size_t)B_*PC_*HW_)      // predicts first: 1572864
#define OUT_IDX_  (OUT_DM_ + (size_t)B_*K_)
#define OUT_LOSS_ (OUT_IDX_ + B_)
#define OUT_DIST_ (OUT_LOSS_ + B_)

// ---- workspace layout (float indices) ----
#define IDX_OFF_  0          // 32 ints
#define DATA_OFF_ 64
// partials: M[np][4096] ++ v[np][192] ++ r[np], np = B*NCH (or B for atomic)

// =====================================================================
// K1: per (b, chunk) accumulate M = sum f f^T, v[pc] = sum f*r, r2 = sum r^2
// 256 threads (4 waves). Each wave computes the FULL 64x64 M over 16 LDS
// rows per tile (8x8 register tile/lane, reads are broadcast b128).
// Double-buffered LDS, issue-early/write-late staging, v from staged regs.
// =====================================================================
template<int NCH, bool ATOMIC>
__global__ __launch_bounds__(256)
void k1_stats(const float* __restrict__ feat, const float* __restrict__ target,
              const float* __restrict__ pred, float* __restrict__ ws) {
    constexpr int NT = (HW_ / NCH) / 64;            // tiles per block
    constexpr size_t NP = ATOMIC ? B_ : (size_t)B_ * NCH;
    const int b     = blockIdx.x / NCH;
    const int chunk = blockIdx.x % NCH;
    const int t    = threadIdx.x;
    const int lane = t & 63;
    const int wv   = t >> 6;
    const int ti   = lane >> 3, tj = lane & 7;
    const int ch0  = t >> 4;       // 0..15
    const int p4   = t & 15;       // 0..15 (float4-group within 64-px tile)
    const int rpc  = t >> 4;       // 0..2 valid when t<48

    __shared__ __align__(16) float fT[2][64][68];   // [buf][row'][ch], row'=(px&3)*16+px>>2
    __shared__ __align__(16) float rT[2][3][68];    // [buf][pc][px] (linear px)

    float acc[8][8];
#pragma unroll
    for (int q = 0; q < 8; ++q)
#pragma unroll
        for (int s = 0; s < 8; ++s) acc[q][s] = 0.f;
    float vacc[4][3];
#pragma unroll
    for (int i = 0; i < 4; ++i) { vacc[i][0] = 0.f; vacc[i][1] = 0.f; vacc[i][2] = 0.f; }
    float rsq = 0.f;

    const float4* feat4 = (const float4*)feat;
    const float4* targ4 = (const float4*)target;
    const float4* pred4 = (const float4*)pred;
    const size_t fb4 = (size_t)b * C_ * HW4_ + (size_t)chunk * (HW4_ / NCH);
    const size_t rb4 = (size_t)b * PC_ * HW4_ + (size_t)chunk * (HW4_ / NCH);

    float4 fst[4];
    float4 rstv = make_float4(0.f, 0.f, 0.f, 0.f);

    // ---------------- prologue: stage tile 0 ----------------
    {
#pragma unroll
        for (int i = 0; i < 4; ++i)
            fst[i] = feat4[fb4 + (size_t)(i * 16 + ch0) * HW4_ + p4];
        if (t < 48) {
            float4 pv = pred4[rb4 + (size_t)rpc * HW4_ + p4];
            float4 tv = targ4[rb4 + (size_t)rpc * HW4_ + p4];
            rstv = make_float4(pv.x - tv.x, pv.y - tv.y, pv.z - tv.z, pv.w - tv.w);
            rsq += rstv.x*rstv.x + rstv.y*rstv.y + rstv.z*rstv.z + rstv.w*rstv.w;
        }
#pragma unroll
        for (int i = 0; i < 4; ++i) {
            const int ch = i * 16 + ch0;
            fT[0][p4     ][ch] = fst[i].x;   // px=4*p4+0 -> row' = 0*16+p4
            fT[0][p4 + 16][ch] = fst[i].y;
            fT[0][p4 + 32][ch] = fst[i].z;
            fT[0][p4 + 48][ch] = fst[i].w;
        }
        if (t < 48) *(float4*)&rT[0][rpc][4 * p4] = rstv;
        __syncthreads();
        const float4 rv0 = *(const float4*)&rT[0][0][4 * p4];
        const float4 rv1 = *(const float4*)&rT[0][1][4 * p4];
        const float4 rv2 = *(const float4*)&rT[0][2][4 * p4];
#pragma unroll
        for (int i = 0; i < 4; ++i) {
            vacc[i][0] += fst[i].x*rv0.x + fst[i].y*rv0.y + fst[i].z*rv0.z + fst[i].w*rv0.w;
            vacc[i][1] += fst[i].x*rv1.x + fst[i].y*rv1.y + fst[i].z*rv1.z + fst[i].w*rv1.w;
            vacc[i][2] += fst[i].x*rv2.x + fst[i].y*rv2.y + fst[i].z*rv2.z + fst[i].w*rv2.w;
        }
    }

    // ---------------- main loop ----------------
    int cur = 0;
    for (int tile = 0; tile < NT; ++tile) {
        if (tile < NT - 1) {               // issue next-tile loads early (hide HBM)
            const size_t tb = (size_t)(tile + 1) * 16;
#pragma unroll
            for (int i = 0; i < 4; ++i)
                fst[i] = feat4[fb4 + (size_t)(i * 16 + ch0) * HW4_ + tb + p4];
            if (t < 48) {
                float4 pv = pred4[rb4 + (size_t)rpc * HW4_ + tb + p4];
                float4 tv = targ4[rb4 + (size_t)rpc * HW4_ + tb + p4];
                rstv = make_float4(pv.x - tv.x, pv.y - tv.y, pv.z - tv.z, pv.w - tv.w);
                rsq += rstv.x*rstv.x + rstv.y*rstv.y + rstv.z*rstv.z + rstv.w*rstv.w;
            }
        }
        // SYRK: wave wv handles rows wv*16 .. wv*16+15 of fT[cur]
#pragma unroll 2
        for (int r = 0; r < 16; ++r) {
            const float* row = &fT[cur][wv * 16 + r][0];
            const float4 a0 = *(const float4*)(row + 8 * ti);
            const float4 a1 = *(const float4*)(row + 8 * ti + 4);
            const float4 b0 = *(const float4*)(row + 8 * tj);
            const float4 b1 = *(const float4*)(row + 8 * tj + 4);
            const float ar[8] = {a0.x, a0.y, a0.z, a0.w, a1.x, a1.y, a1.z, a1.w};
            const float bc[8] = {b0.x, b0.y, b0.z, b0.w, b1.x, b1.y, b1.z, b1.w};
#pragma unroll
            for (int q = 0; q < 8; ++q)
#pragma unroll
                for (int s = 0; s < 8; ++s)
                    acc[q][s] += ar[q] * bc[s];
        }
        if (tile < NT - 1) {
            const int nx = cur ^ 1;
#pragma unroll
            for (int i = 0; i < 4; ++i) {
                const int ch = i * 16 + ch0;
                fT[nx][p4     ][ch] = fst[i].x;
                fT[nx][p4 + 16][ch] = fst[i].y;
                fT[nx][p4 + 32][ch] = fst[i].z;
                fT[nx][p4 + 48][ch] = fst[i].w;
            }
            if (t < 48) *(float4*)&rT[nx][rpc][4 * p4] = rstv;
            __syncthreads();
            const float4 rv0 = *(const float4*)&rT[nx][0][4 * p4];
            const float4 rv1 = *(const float4*)&rT[nx][1][4 * p4];
            const float4 rv2 = *(const float4*)&rT[nx][2][4 * p4];
#pragma unroll
            for (int i = 0; i < 4; ++i) {
                vacc[i][0] += fst[i].x*rv0.x + fst[i].y*rv0.y + fst[i].z*rv0.z + fst[i].w*rv0.w;
                vacc[i][1] += fst[i].x*rv1.x + fst[i].y*rv1.y + fst[i].z*rv1.z + fst[i].w*rv1.w;
                vacc[i][2] += fst[i].x*rv2.x + fst[i].y*rv2.y + fst[i].z*rv2.z + fst[i].w*rv2.w;
            }
            cur = nx;
        }
    }

    // ---------------- cross-wave reduce of acc (deterministic) ----------------
    __syncthreads();
    float (*redA)[68] = fT[0];
    float (*redB)[68] = fT[1];
    if (wv == 2) {
#pragma unroll
        for (int q = 0; q < 8; ++q) {
            *(float4*)&redA[8*ti + q][8*tj]     = make_float4(acc[q][0], acc[q][1], acc[q][2], acc[q][3]);
            *(float4*)&redA[8*ti + q][8*tj + 4] = make_float4(acc[q][4], acc[q][5], acc[q][6], acc[q][7]);
        }
    }
    if (wv == 3) {
#pragma unroll
        for (int q = 0; q < 8; ++q) {
            *(float4*)&redB[8*ti + q][8*tj]     = make_float4(acc[q][0], acc[q][1], acc[q][2], acc[q][3]);
            *(float4*)&redB[8*ti + q][8*tj + 4] = make_float4(acc[q][4], acc[q][5], acc[q][6], acc[q][7]);
        }
    }
    __syncthreads();
    if (wv == 0) {
#pragma unroll
        for (int q = 0; q < 8; ++q) {
            const float4 x0 = *(const float4*)&redA[8*ti + q][8*tj];
            const float4 x1 = *(const float4*)&redA[8*ti + q][8*tj + 4];
            acc[q][0] += x0.x; acc[q][1] += x0.y; acc[q][2] += x0.z; acc[q][3] += x0.w;
            acc[q][4] += x1.x; acc[q][5] += x1.y; acc[q][6] += x1.z; acc[q][7] += x1.w;
        }
    }
    if (wv == 1) {
#pragma unroll
        for (int q = 0; q < 8; ++q) {
            const float4 x0 = *(const float4*)&redB[8*ti + q][8*tj];
            const float4 x1 = *(const float4*)&redB[8*ti + q][8*tj + 4];
            acc[q][0] += x0.x; acc[q][1] += x0.y; acc[q][2] += x0.z; acc[q][3] += x0.w;
            acc[q][4] += x1.x; acc[q][5] += x1.y; acc[q][6] += x1.z; acc[q][7] += x1.w;
        }
    }
    __syncthreads();
    if (wv == 1) {
#pragma unroll
        for (int q = 0; q < 8; ++q) {
            *(float4*)&redA[8*ti + q][8*tj]     = make_float4(acc[q][0], acc[q][1], acc[q][2], acc[q][3]);
            *(float4*)&redA[8*ti + q][8*tj + 4] = make_float4(acc[q][4], acc[q][5], acc[q][6], acc[q][7]);
        }
    }
    __syncthreads();
    const size_t slot = ATOMIC ? (size_t)b : (size_t)b * NCH + chunk;
    if (wv == 0) {
#pragma unroll
        for (int q = 0; q < 8; ++q) {
            const float4 x0 = *(const float4*)&redA[8*ti + q][8*tj];
            const float4 x1 = *(const float4*)&redA[8*ti + q][8*tj + 4];
            acc[q][0] += x0.x; acc[q][1] += x0.y; acc[q][2] += x0.z; acc[q][3] += x0.w;
            acc[q][4] += x1.x; acc[q][5] += x1.y; acc[q][6] += x1.z; acc[q][7] += x1.w;
        }
        float* Mp = ws + DATA_OFF_ + slot * 4096;
        if (!ATOMIC) {
#pragma unroll
            for (int q = 0; q < 8; ++q) {
                *(float4*)&Mp[(8*ti + q) * 64 + 8*tj]     = make_float4(acc[q][0], acc[q][1], acc[q][2], acc[q][3]);
                *(float4*)&Mp[(8*ti + q) * 64 + 8*tj + 4] = make_float4(acc[q][4], acc[q][5], acc[q][6], acc[q][7]);
            }
        } else {
#pragma unroll
            for (int q = 0; q < 8; ++q)
#pragma unroll
                for (int s = 0; s < 8; ++s)
                    atomicAdd(&Mp[(8*ti + q) * 64 + 8*tj + s], acc[q][s]);
        }
    }

    // ---------------- v reduce: sum across the 16 threads sharing ch-set ----------------
#pragma unroll
    for (int off = 8; off >= 1; off >>= 1) {
#pragma unroll
        for (int i = 0; i < 4; ++i) {
            vacc[i][0] += __shfl_xor(vacc[i][0], off);
            vacc[i][1] += __shfl_xor(vacc[i][1], off);
            vacc[i][2] += __shfl_xor(vacc[i][2], off);
        }
    }
    float* vp = ws + DATA_OFF_ + NP * 4096 + slot * 192;
    if ((t & 15) == 0) {
        const int g = t >> 4;
#pragma unroll
        for (int i = 0; i < 4; ++i)
#pragma unroll
            for (int pc = 0; pc < 3; ++pc) {
                if (!ATOMIC) vp[pc * 64 + i * 16 + g] = vacc[i][pc];
                else         atomicAdd(&vp[pc * 64 + i * 16 + g], vacc[i][pc]);
            }
    }
    if (wv == 0) {
#pragma unroll
        for (int off = 32; off >= 1; off >>= 1) rsq += __shfl_xor(rsq, off);
        if (t == 0) {
            float* rp = ws + DATA_OFF_ + NP * 4096 + NP * 192 + slot;
            if (!ATOMIC) *rp = rsq;
            else         atomicAdd(rp, rsq);
        }
    }
}

// =====================================================================
// K2: per-b reduce partials; dist_k = (w_k^T M w_k + 2 w_k.v + r2)/N;
// argmin; write dm/idx/loss/distances.
// =====================================================================
template<int NCHR>
__global__ __launch_bounds__(256)
void k2_dist(const float* __restrict__ weight, float* __restrict__ ws,
             float* __restrict__ dout) {
    constexpr size_t NP = (size_t)B_ * NCHR;
    const int b = blockIdx.x, t = threadIdx.x;
    __shared__ __align__(16) float Ml[64][64];
    __shared__ __align__(16) float vl[3][64];
    __shared__ float red[3][64];
    __shared__ float rl;

    const float4* Mp4 = (const float4*)(ws + DATA_OFF_ + (size_t)b * NCHR * 4096);
    float4* Ml4 = (float4*)&Ml[0][0];
#pragma unroll
    for (int s = 0; s < 4; ++s) {
        const int idx4 = s * 256 + t;
        float4 a = make_float4(0.f, 0.f, 0.f, 0.f);
        for (int ch = 0; ch < NCHR; ++ch) {
            const float4 m = Mp4[(size_t)ch * 1024 + idx4];
            a.x += m.x; a.y += m.y; a.z += m.z; a.w += m.w;
        }
        Ml4[idx4] = a;
    }
    const float* vbase = ws + DATA_OFF_ + NP * 4096 + (size_t)b * NCHR * 192;
    if (t < 192) {
        float a = 0.f;
        for (int ch = 0; ch < NCHR; ++ch) a += vbase[ch * 192 + t];
        (&vl[0][0])[t] = a;
    }
    if (t == 0) {
        const float* rbase = ws + DATA_OFF_ + NP * 4096 + NP * 192 + (size_t)b * NCHR;
        float a = 0.f;
        for (int ch = 0; ch < NCHR; ++ch) a += rbase[ch];
        rl = a;
    }
    __syncthreads();

    if (t < 192) {
        const int k = t & 63, pc = t >> 6;
        const float4* wr = (const float4*)(weight + (size_t)(3 * k + pc) * 64);
        float4 w[16];
#pragma unroll
        for (int j = 0; j < 16; ++j) w[j] = wr[j];
        float s = 0.f;
#pragma unroll 2
        for (int i4 = 0; i4 < 16; ++i4) {
            const float wi[4] = {w[i4].x, w[i4].y, w[i4].z, w[i4].w};
#pragma unroll
            for (int ii = 0; ii < 4; ++ii) {
                const int i = i4 * 4 + ii;
                const float4* Mr = (const float4*)&Ml[i][0];
                float4 ya = make_float4(0.f, 0.f, 0.f, 0.f);
#pragma unroll
                for (int j = 0; j < 16; ++j) {
                    ya.x += Mr[j].x * w[j].x; ya.y += Mr[j].y * w[j].y;
                    ya.z += Mr[j].z * w[j].z; ya.w += Mr[j].w * w[j].w;
                }
                s += wi[ii] * (ya.x + ya.y + ya.z + ya.w);
            }
        }
        const float4* vl4 = (const float4*)&vl[pc][0];
        float4 sv = make_float4(0.f, 0.f, 0.f, 0.f);
#pragma unroll
        for (int j = 0; j < 16; ++j) {
            sv.x += vl4[j].x * w[j].x; sv.y += vl4[j].y * w[j].y;
            sv.z += vl4[j].z * w[j].z; sv.w += vl4[j].w * w[j].w;
        }
        red[pc][k] = s + 2.f * (sv.x + sv.y + sv.z + sv.w);
    }
    __syncthreads();
    if (t < 64) {
        float d = (red[0][t] + red[1][t] + red[2][t] + rl) * INV_N_;
        dout[OUT_DM_ + (size_t)b * 64 + t] = d;
        int idx = t;
#pragma unroll
        for (int off = 32; off >= 1; off >>= 1) {
            const float od = __shfl_xor(d, off);
            const int   oi = __shfl_xor(idx, off);
            if (od < d || (od == d && oi < idx)) { d = od; idx = oi; }
        }
        if (t == 0) {
            ((int*)ws)[IDX_OFF_ + b] = idx;
            dout[OUT_IDX_  + b] = (float)idx;
            dout[OUT_LOSS_ + b] = d;   // loss == distances mathematically
            dout[OUT_DIST_ + b] = d;
        }
    }
}

// =====================================================================
// K4: recompute winning candidate only; predicts = f.w_best + predict_last
// =====================================================================
__global__ __launch_bounds__(256)
void k4_pred(const float* __restrict__ feat, const float* __restrict__ predl,
             const float* __restrict__ weight, const float* __restrict__ ws,
             float* __restrict__ dout) {
    const int b   = blockIdx.x >> 4;
    const int blk = blockIdx.x & 15;
    const int t   = threadIdx.x;
    __shared__ float wl[PC_][64];
    const int kbest = ((const int*)ws)[IDX_OFF_ + b];
    if (t < 192) {
        const int pc = t >> 6, c = t & 63;
        wl[pc][c] = weight[(size_t)(kbest * 3 + pc) * 64 + c];
    }
    __syncthreads();
    const int hw4 = blk * 256 + t;
    const float4* f4 = (const float4*)feat;
    const size_t base4 = (size_t)b * C_ * HW4_ + hw4;
    float4 a0 = {0,0,0,0}, a1 = {0,0,0,0}, a2 = {0,0,0,0};
#pragma unroll 4
    for (int c = 0; c < C_; ++c) {
        const float4 f = f4[base4 + (size_t)c * HW4_];
        const float w0 = wl[0][c], w1 = wl[1][c], w2 = wl[2][c];
        a0.x += f.x*w0; a0.y += f.y*w0; a0.z += f.z*w0; a0.w += f.w*w0;
        a1.x += f.x*w1; a1.y += f.y*w1; a1.z += f.z*w1; a1.w += f.w*w1;
        a2.x += f.x*w2; a2.y += f.y*w2; a2.z += f.z*w2; a2.w += f.w*w2;
    }
    const float4* p4 = (const float4*)predl;
    float4* o4 = (float4*)dout;
    const size_t ob = (size_t)b * PC_ * HW4_ + hw4;
    float4 pl;
    pl = p4[ob];        a0.x += pl.x; a0.y += pl.y; a0.z += pl.z; a0.w += pl.w; o4[ob]        = a0;
    pl = p4[ob + 4096]; a1.x += pl.x; a1.y += pl.y; a1.z += pl.z; a1.w += pl.w; o4[ob + 4096] = a1;
    pl = p4[ob + 8192]; a2.x += pl.x; a2.y += pl.y; a2.z += pl.z; a2.w += pl.w; o4[ob + 8192] = a2;
}

extern "C" void kernel_launch(void* const* d_in, const int* in_sizes, int n_in,
                              void* d_out, int out_size, void* d_ws, size_t ws_size,
                              hipStream_t stream) {
    const float* feat   = (const float*)d_in[0];
    const float* target = (const float*)d_in[1];
    const float* predl  = (const float*)d_in[2];
    const float* weight = (const float*)d_in[3];
    float* out = (float*)d_out;
    float* wsf = (float*)d_ws;

    const size_t need32 = (DATA_OFF_ + (size_t)B_ * 32 * (4096 + 192 + 1)) * sizeof(float);
    const size_t need16 = (DATA_OFF_ + (size_t)B_ * 16 * (4096 + 192 + 1)) * sizeof(float);

    if (ws_size >= need32) {
        hipLaunchKernelGGL((k1_stats<32, false>), dim3(B_ * 32), dim3(256), 0, stream,
                           feat, target, predl, wsf);
        hipLaunchKernelGGL((k2_dist<32>), dim3(B_), dim3(256), 0, stream,
                           weight, wsf, out);
    } else if (ws_size >= need16) {
        hipLaunchKernelGGL((k1_stats<16, false>), dim3(B_ * 16), dim3(256), 0, stream,
                           feat, target, predl, wsf);
        hipLaunchKernelGGL((k2_dist<16>), dim3(B_), dim3(256), 0, stream,
                           weight, wsf, out);
    } else {
        hipMemsetAsync(wsf + DATA_OFF_, 0,
                       (size_t)B_ * (4096 + 192 + 1) * sizeof(float), stream);
        hipLaunchKernelGGL((k1_stats<32, true>), dim3(B_ * 32), dim3(256), 0, stream,
                           feat, target, predl, wsf);
        hipLaunchKernelGGL((k2_dist<1>), dim3(B_), dim3(256), 0, stream,
                           weight, wsf, out);
    }
    hipLaunchKernelGGL(k4_pred, dim3(B_ * 16), dim3(256), 0, stream,
                       feat, predl, weight, wsf, out);
}

// Round 3
// 113.092 us; speedup vs baseline: 1.4285x; 1.2837x over previous
//
#include <hip/hip_runtime.h>
#include <cstddef>
#include <cstdint>

#define B_ 32
#define C_ 64
#define HW_ 16384
#define HW4_ 4096
#define PC_ 3
#define NCH_ 16
#define INV_N_ (1.0f/49152.0f)

typedef __attribute__((ext_vector_type(8))) short bf16x8;
typedef __attribute__((ext_vector_type(4))) float f32x4;

// ---- output layout (float indices) ----
#define OUT_DM_   ((size_t)B_*PC_*HW_)      // predicts first: 1572864
#define OUT_IDX_  (OUT_DM_ + (size_t)B_*64)
#define OUT_LOSS_ (OUT_IDX_ + B_)
#define OUT_DIST_ (OUT_LOSS_ + B_)

// ---- workspace layout (float indices) ----
#define IDX_OFF_  0                         // 32 ints
#define SLOT_     4304                      // 4096 M + 192 v + 3 r (+pad, 16B-aligned)
#define SLOT_USED_ 4291
#define REDU_OFF_ ((size_t)64)
#define PART_OFF_ (REDU_OFF_ + (size_t)B_*SLOT_)
// total: 64 + 32*4304 + 512*4304 floats = 9.37 MB (ws proven >= 17.6 MB in R2)

// split f32 -> hi/lo bf16 (RNE), covers top 16 mantissa bits
__device__ __forceinline__ void split2(float x, short& hs, short& ls) {
    unsigned u = __float_as_uint(x);
    unsigned hr = (u + 0x7FFFu + ((u >> 16) & 1u)) >> 16;
    float hf = __uint_as_float(hr << 16);
    float r = x - hf;                       // exact (Sterbenz)
    unsigned v = __float_as_uint(r);
    unsigned lr = (v + 0x7FFFu + ((v >> 16) & 1u)) >> 16;
    hs = (short)hr; ls = (short)lr;
}

// 4-pass split-bf16 product accumulate: C += (Ah+Al)*(Bh+Bl)
__device__ __forceinline__ f32x4 mm4(bf16x8 ah, bf16x8 al, bf16x8 bh, bf16x8 bl, f32x4 c) {
    c = __builtin_amdgcn_mfma_f32_16x16x32_bf16(ah, bh, c, 0, 0, 0);
    c = __builtin_amdgcn_mfma_f32_16x16x32_bf16(ah, bl, c, 0, 0, 0);
    c = __builtin_amdgcn_mfma_f32_16x16x32_bf16(al, bh, c, 0, 0, 0);
    c = __builtin_amdgcn_mfma_f32_16x16x32_bf16(al, bl, c, 0, 0, 0);
    return c;
}

__device__ __forceinline__ void acc_dump(float* d, const f32x4* a) {
#pragma unroll
    for (int tt = 0; tt < 15; ++tt)
#pragma unroll
        for (int q = 0; q < 4; ++q) d[tt * 4 + q] = a[tt][q];
}
__device__ __forceinline__ void acc_add(f32x4* a, const float* d) {
#pragma unroll
    for (int tt = 0; tt < 15; ++tt)
#pragma unroll
        for (int q = 0; q < 4; ++q) a[tt][q] += d[tt * 4 + q];
}

// =====================================================================
// K1: per (b, chunk of 16): M = sum f f^T (triangular tiles), v = sum f*r,
// rsq = sum r^2 — all via split-bf16 MFMA, no LDS in main loop.
// 8 waves, each owns 128 pixels = 4 K-steps of 32.
// =====================================================================
__global__ __launch_bounds__(512)
void k1_stats(const float* __restrict__ feat, const float* __restrict__ target,
              const float* __restrict__ pred, float* __restrict__ ws) {
    const int b = blockIdx.x >> 4, chunk = blockIdx.x & 15;
    const int t = threadIdx.x, wv = t >> 6, lane = t & 63;
    const int lr = lane & 15, lg = lane >> 4;

    // tiles: 0-9 = M (gi<=gj), 10-13 = v (r x Fg), 14 = r x r
    f32x4 acc[15];
    const f32x4 zz = {0.f, 0.f, 0.f, 0.f};
#pragma unroll
    for (int i = 0; i < 15; ++i) acc[i] = zz;

    const int px_wave = chunk * 1024 + wv * 128;

    for (int step = 0; step < 4; ++step) {
        const int px = px_wave + step * 32 + lg * 8;
        float f[4][8];
#pragma unroll
        for (int g = 0; g < 4; ++g) {
            const float4* p = (const float4*)(feat + (size_t)(b * 64 + g * 16 + lr) * HW_ + px);
            const float4 x = p[0], y = p[1];
            f[g][0] = x.x; f[g][1] = x.y; f[g][2] = x.z; f[g][3] = x.w;
            f[g][4] = y.x; f[g][5] = y.y; f[g][6] = y.z; f[g][7] = y.w;
        }
        float rr[8];
        if (lr < 3) {
            const float4* pp = (const float4*)(pred   + (size_t)(b * 3 + lr) * HW_ + px);
            const float4* tp = (const float4*)(target + (size_t)(b * 3 + lr) * HW_ + px);
            const float4 p0 = pp[0], p1 = pp[1], t0 = tp[0], t1 = tp[1];
            rr[0] = p0.x - t0.x; rr[1] = p0.y - t0.y; rr[2] = p0.z - t0.z; rr[3] = p0.w - t0.w;
            rr[4] = p1.x - t1.x; rr[5] = p1.y - t1.y; rr[6] = p1.z - t1.z; rr[7] = p1.w - t1.w;
        } else {
#pragma unroll
            for (int i = 0; i < 8; ++i) rr[i] = 0.f;
        }
        bf16x8 Fh[4], Fl[4], Rh, Rl;
#pragma unroll
        for (int g = 0; g < 4; ++g)
#pragma unroll
            for (int i = 0; i < 8; ++i) {
                short h, l; split2(f[g][i], h, l);
                Fh[g][i] = h; Fl[g][i] = l;
            }
#pragma unroll
        for (int i = 0; i < 8; ++i) {
            short h, l; split2(rr[i], h, l);
            Rh[i] = h; Rl[i] = l;
        }

        acc[0]  = mm4(Fh[0], Fl[0], Fh[0], Fl[0], acc[0]);
        acc[1]  = mm4(Fh[0], Fl[0], Fh[1], Fl[1], acc[1]);
        acc[2]  = mm4(Fh[0], Fl[0], Fh[2], Fl[2], acc[2]);
        acc[3]  = mm4(Fh[0], Fl[0], Fh[3], Fl[3], acc[3]);
        acc[4]  = mm4(Fh[1], Fl[1], Fh[1], Fl[1], acc[4]);
        acc[5]  = mm4(Fh[1], Fl[1], Fh[2], Fl[2], acc[5]);
        acc[6]  = mm4(Fh[1], Fl[1], Fh[3], Fl[3], acc[6]);
        acc[7]  = mm4(Fh[2], Fl[2], Fh[2], Fl[2], acc[7]);
        acc[8]  = mm4(Fh[2], Fl[2], Fh[3], Fl[3], acc[8]);
        acc[9]  = mm4(Fh[3], Fl[3], Fh[3], Fl[3], acc[9]);
        acc[10] = mm4(Rh, Rl, Fh[0], Fl[0], acc[10]);
        acc[11] = mm4(Rh, Rl, Fh[1], Fl[1], acc[11]);
        acc[12] = mm4(Rh, Rl, Fh[2], Fl[2], acc[12]);
        acc[13] = mm4(Rh, Rl, Fh[3], Fl[3], acc[13]);
        acc[14] = mm4(Rh, Rl, Rh, Rl, acc[14]);
    }

    // ---- deterministic 8-wave tree reduce via 2 LDS buffers ----
    __shared__ __align__(16) float buf[2][64][68];
    float* b0 = &buf[0][lane][0];
    float* b1 = &buf[1][lane][0];

    if (wv == 4) acc_dump(b0, acc);
    if (wv == 5) acc_dump(b1, acc);
    __syncthreads();
    if (wv == 0) acc_add(acc, b0);
    if (wv == 1) acc_add(acc, b1);
    __syncthreads();
    if (wv == 6) acc_dump(b0, acc);
    if (wv == 7) acc_dump(b1, acc);
    __syncthreads();
    if (wv == 2) acc_add(acc, b0);
    if (wv == 3) acc_add(acc, b1);
    __syncthreads();
    if (wv == 2) acc_dump(b0, acc);
    if (wv == 3) acc_dump(b1, acc);
    __syncthreads();
    if (wv == 0) acc_add(acc, b0);
    if (wv == 1) acc_add(acc, b1);
    __syncthreads();
    if (wv == 1) acc_dump(b0, acc);
    __syncthreads();

    if (wv == 0) {
        acc_add(acc, b0);
        float* P = ws + PART_OFF_ + (size_t)blockIdx.x * SLOT_;
        const int TI[10] = {0,0,0,0,1,1,1,2,2,3};
        const int TJ[10] = {0,1,2,3,1,2,3,2,3,3};
#pragma unroll
        for (int tt = 0; tt < 10; ++tt) {
            const int gi = TI[tt], gj = TJ[tt];
#pragma unroll
            for (int q = 0; q < 4; ++q) {
                const int i = gi * 16 + lg * 4 + q;
                const int j = gj * 16 + lr;
                const float val = acc[tt][q];
                P[i * 64 + j] = val;
                if (gi != gj) P[j * 64 + i] = val;
            }
        }
        if (lg == 0) {   // v: D rows 0..2 live in lanes 0-15, regs 0..2
#pragma unroll
            for (int gj = 0; gj < 4; ++gj) {
                P[4096 + 0 * 64 + gj * 16 + lr] = acc[10 + gj][0];
                P[4096 + 1 * 64 + gj * 16 + lr] = acc[10 + gj][1];
                P[4096 + 2 * 64 + gj * 16 + lr] = acc[10 + gj][2];
            }
        }
        if (lane == 0) P[4288] = acc[14][0];   // r[0][0]
        if (lane == 1) P[4289] = acc[14][1];   // r[1][1]
        if (lane == 2) P[4290] = acc[14][2];   // r[2][2]
    }
}

// =====================================================================
// K2a: grid-wide reduce of 16 partial slots per b
// =====================================================================
__global__ __launch_bounds__(256)
void k2a_reduce(float* __restrict__ ws) {
    const int b = blockIdx.x / 17, blk = blockIdx.x % 17;
    const int pos = blk * 256 + threadIdx.x;
    if (pos >= SLOT_USED_) return;
    const float* P = ws + PART_OFF_ + (size_t)b * NCH_ * SLOT_ + pos;
    float s = 0.f;
#pragma unroll
    for (int c = 0; c < NCH_; ++c) s += P[(size_t)c * SLOT_];
    ws[REDU_OFF_ + (size_t)b * SLOT_ + pos] = s;
}

// =====================================================================
// K2b: dist_k = (w_k^T M w_k + 2 w_k.v + rsq)/N; argmin; outputs.
// =====================================================================
__global__ __launch_bounds__(256)
void k2b_dist(const float* __restrict__ weight, float* __restrict__ ws,
              float* __restrict__ dout) {
    const int b = blockIdx.x, t = threadIdx.x;
    __shared__ __align__(16) float Ml[64][64];
    __shared__ __align__(16) float vl[3][64];
    __shared__ float red[3][64];
    __shared__ float rl;

    const float* R = ws + REDU_OFF_ + (size_t)b * SLOT_;
    const float4* R4 = (const float4*)R;
    float4* Ml4 = (float4*)&Ml[0][0];
#pragma unroll
    for (int s = 0; s < 4; ++s) Ml4[s * 256 + t] = R4[s * 256 + t];
    if (t < 192) (&vl[0][0])[t] = R[4096 + t];
    if (t == 0) rl = R[4288] + R[4289] + R[4290];
    __syncthreads();

    if (t < 192) {
        const int k = t & 63, pc = t >> 6;
        const float4* wr = (const float4*)(weight + (size_t)(3 * k + pc) * 64);
        float4 w[16];
#pragma unroll
        for (int j = 0; j < 16; ++j) w[j] = wr[j];
        float s = 0.f;
#pragma unroll 2
        for (int i4 = 0; i4 < 16; ++i4) {
            const float wi[4] = {w[i4].x, w[i4].y, w[i4].z, w[i4].w};
#pragma unroll
            for (int ii = 0; ii < 4; ++ii) {
                const int i = i4 * 4 + ii;
                const float4* Mr = (const float4*)&Ml[i][0];
                float4 ya = make_float4(0.f, 0.f, 0.f, 0.f);
#pragma unroll
                for (int j = 0; j < 16; ++j) {
                    ya.x += Mr[j].x * w[j].x; ya.y += Mr[j].y * w[j].y;
                    ya.z += Mr[j].z * w[j].z; ya.w += Mr[j].w * w[j].w;
                }
                s += wi[ii] * (ya.x + ya.y + ya.z + ya.w);
            }
        }
        const float4* vl4 = (const float4*)&vl[pc][0];
        float4 sv = make_float4(0.f, 0.f, 0.f, 0.f);
#pragma unroll
        for (int j = 0; j < 16; ++j) {
            sv.x += vl4[j].x * w[j].x; sv.y += vl4[j].y * w[j].y;
            sv.z += vl4[j].z * w[j].z; sv.w += vl4[j].w * w[j].w;
        }
        red[pc][k] = s + 2.f * (sv.x + sv.y + sv.z + sv.w);
    }
    __syncthreads();
    if (t < 64) {
        float d = (red[0][t] + red[1][t] + red[2][t] + rl) * INV_N_;
        dout[OUT_DM_ + (size_t)b * 64 + t] = d;
        int idx = t;
#pragma unroll
        for (int off = 32; off >= 1; off >>= 1) {
            const float od = __shfl_xor(d, off);
            const int   oi = __shfl_xor(idx, off);
            if (od < d || (od == d && oi < idx)) { d = od; idx = oi; }
        }
        if (t == 0) {
            ((int*)ws)[IDX_OFF_ + b] = idx;
            dout[OUT_IDX_  + b] = (float)idx;
            dout[OUT_LOSS_ + b] = d;   // loss == distances mathematically
            dout[OUT_DIST_ + b] = d;
        }
    }
}

// =====================================================================
// K4: recompute winning candidate only; predicts = f.w_best + predict_last
// =====================================================================
__global__ __launch_bounds__(256)
void k4_pred(const float* __restrict__ feat, const float* __restrict__ predl,
             const float* __restrict__ weight, const float* __restrict__ ws,
             float* __restrict__ dout) {
    const int b   = blockIdx.x >> 4;
    const int blk = blockIdx.x & 15;
    const int t   = threadIdx.x;
    __shared__ float wl[PC_][64];
    const int kbest = ((const int*)ws)[IDX_OFF_ + b];
    if (t < 192) {
        const int pc = t >> 6, c = t & 63;
        wl[pc][c] = weight[(size_t)(kbest * 3 + pc) * 64 + c];
    }
    __syncthreads();
    const int hw4 = blk * 256 + t;
    const float4* f4 = (const float4*)feat;
    const size_t base4 = (size_t)b * C_ * HW4_ + hw4;
    float4 a0 = {0,0,0,0}, a1 = {0,0,0,0}, a2 = {0,0,0,0};
#pragma unroll 4
    for (int c = 0; c < C_; ++c) {
        const float4 f = f4[base4 + (size_t)c * HW4_];
        const float w0 = wl[0][c], w1 = wl[1][c], w2 = wl[2][c];
        a0.x += f.x*w0; a0.y += f.y*w0; a0.z += f.z*w0; a0.w += f.w*w0;
        a1.x += f.x*w1; a1.y += f.y*w1; a1.z += f.z*w1; a1.w += f.w*w1;
        a2.x += f.x*w2; a2.y += f.y*w2; a2.z += f.z*w2; a2.w += f.w*w2;
    }
    const float4* p4 = (const float4*)predl;
    float4* o4 = (float4*)dout;
    const size_t ob = (size_t)b * PC_ * HW4_ + hw4;
    float4 pl;
    pl = p4[ob];        a0.x += pl.x; a0.y += pl.y; a0.z += pl.z; a0.w += pl.w; o4[ob]        = a0;
    pl = p4[ob + 4096]; a1.x += pl.x; a1.y += pl.y; a1.z += pl.z; a1.w += pl.w; o4[ob + 4096] = a1;
    pl = p4[ob + 8192]; a2.x += pl.x; a2.y += pl.y; a2.z += pl.z; a2.w += pl.w; o4[ob + 8192] = a2;
}

extern "C" void kernel_launch(void* const* d_in, const int* in_sizes, int n_in,
                              void* d_out, int out_size, void* d_ws, size_t ws_size,
                              hipStream_t stream) {
    const float* feat   = (const float*)d_in[0];
    const float* target = (const float*)d_in[1];
    const float* predl  = (const float*)d_in[2];
    const float* weight = (const float*)d_in[3];
    float* out = (float*)d_out;
    float* wsf = (float*)d_ws;
    (void)ws_size;

    hipLaunchKernelGGL(k1_stats, dim3(B_ * NCH_), dim3(512), 0, stream,
                       feat, target, predl, wsf);
    hipLaunchKernelGGL(k2a_reduce, dim3(B_ * 17), dim3(256), 0, stream, wsf);
    hipLaunchKernelGGL(k2b_dist, dim3(B_), dim3(256), 0, stream,
                       weight, wsf, out);
    hipLaunchKernelGGL(k4_pred, dim3(B_ * 16), dim3(256), 0, stream,
                       feat, predl, weight, wsf, out);
}